// Round 7
// baseline (165.579 us; speedup 1.0000x reference)
//
#include <hip/hip_runtime.h>

// (B,N,D,L) = (32,1000,256,3), all fp32.
// d_in: [0]=x (unused), [1]=node_feature, [2]=Ws (L,D,D), [3]=bs (L,D).
// Math collapses (A_norm = ones/N):
//   h[b,:] = MLP(mean_n nf[b,n,:]);  out0 = nf + h (broadcast);  out1 = nf.
//
// R5 post-mortem: k_all=79us for ~17us of traffic. Critical path = winner MLP:
// 256-deep serial FMA chain, W cold in L2 (HBM latency), 50-deep sc1 reduce.
// R6/R7: (1) every block pre-warms a 16KB W slice into its XCD L2 in phase A;
// (2) winner uses 4 interleaved accumulators (chain 256->64) + unroll-8 load
// pipelining; 2-chain partial reduce; (3) nf/out0/out1 nontemporal so the
// streaming doesn't evict the warmed W. R7 fixes R6's compile error:
// __builtin_nontemporal_* requires NATIVE vector types (ext_vector_type),
// not HIP_vector_type. Sync design unchanged from R5 (relaxed sc1 only, zero
// cache-maintenance ops; ordering via the vmcnt(0) drain in __syncthreads).
#define BB 32
#define NN 1000
#define DD 256
#define SS 50                   // chunks per batch; SS*RPS == NN
#define RPS 20                  // rows per chunk
#define ELEMS (BB * NN * DD)    // 8,192,000 floats per output tensor
#define WF4 (3 * DD * DD / 4)   // 49152 float4 in Ws

typedef float f4 __attribute__((ext_vector_type(4)));   // native vec for NT ops

#define LD_A(p)     __hip_atomic_load((p),      __ATOMIC_RELAXED, __HIP_MEMORY_SCOPE_AGENT)
#define ST_A(p, v)  __hip_atomic_store((p), (v), __ATOMIC_RELAXED, __HIP_MEMORY_SCOPE_AGENT)

// ---- K0: zero the 32 counters + 32 flags (64 words). Replayed per-iter. ----
__global__ __launch_bounds__(64) void k_init(unsigned* __restrict__ sync) {
    sync[threadIdx.x] = 0u;
}

__global__ __launch_bounds__(256, 7) void k_all(const f4* __restrict__ nf4,
                                                const float* __restrict__ Ws,
                                                const float* __restrict__ bsv,
                                                f4* __restrict__ out0_4,
                                                f4* __restrict__ out1_4,
                                                float* __restrict__ partials,
                                                float* __restrict__ hws,
                                                unsigned* __restrict__ ctr,
                                                unsigned* __restrict__ flag) {
    const int s = blockIdx.x, b = blockIdx.y, t = threadIdx.x;
    const int r4 = t >> 6, c = t & 63;

    __shared__ __align__(16) float red[1024];
    __shared__ __align__(16) float h[2][DD];
    __shared__ __align__(16) float hsh[DD];
    __shared__ unsigned oldv;

    // ---- Phase A: nf -> regs (nontemporal), out1 = nf, partial col sums ----
    f4 vv[5];
    f4 acc = (f4)(0.f);
#pragma unroll
    for (int i = 0; i < 5; i++) {
        const int n = s * RPS + i * 4 + r4;
        const int idx = (b * NN + n) * (DD / 4) + c;
        f4 v = __builtin_nontemporal_load(&nf4[idx]);
        vv[i] = v;
        __builtin_nontemporal_store(v, &out1_4[idx]);   // output 1 (= nf)
        acc += v;
    }
    // warm this block's W slice into the local XCD L2 (plain cached loads;
    // 50 slices x 16KB cover all 768KB; ~200 blocks/XCD => full coverage).
    {
        const f4* W4 = (const f4*)Ws;
#pragma unroll
        for (int i = 0; i < 4; i++) {
            int idx = s * 1024 + i * 256 + t;
            if (idx >= WF4) idx -= WF4;
            f4 w = W4[idx];
            asm volatile("" :: "v"(w.x), "v"(w.y), "v"(w.z), "v"(w.w));
        }
    }
    ((f4*)red)[r4 * 64 + c] = acc;          // red[r4*256 + c*4 + j]
    __syncthreads();
    const float sum = red[t] + red[256 + t] + red[512 + t] + red[768 + t];
    ST_A(&partials[(b * SS + s) * DD + t], sum);   // sc1 write-through
    __syncthreads();                    // vmcnt(0): stores at coherence point
    if (t == 0)
        oldv = __hip_atomic_fetch_add(&ctr[b], 1u,
                                      __ATOMIC_RELAXED, __HIP_MEMORY_SCOPE_AGENT);
    __syncthreads();

    // ---- Phase B (last arriver of this b): 3-layer MLP, latency-optimized ----
    if (oldv == (unsigned)(SS - 1)) {            // block-uniform branch
        float a0 = 0.f, a1 = 0.f;                // 2 chains, 25 deep each
#pragma unroll 10
        for (int sp = 0; sp < SS; sp += 2) {
            a0 += LD_A(&partials[(b * SS + sp) * DD + t]);
            a1 += LD_A(&partials[(b * SS + sp + 1) * DD + t]);
        }
        h[0][t] = (a0 + a1) * (1.0f / (float)NN);
        __syncthreads();
        int cur = 0;
        for (int l = 0; l < 3; l++) {
            const float* __restrict__ W = Ws + l * DD * DD;
            float c0 = 0.f, c1 = 0.f, c2 = 0.f, c3 = 0.f;  // chain 256 -> 64
#pragma unroll 8
            for (int k4 = 0; k4 < DD / 4; k4++) {
                const float* Wk = W + (k4 * 4) * DD + t;   // L2-warm
                c0 = fmaf(h[cur][k4 * 4 + 0], Wk[0 * DD], c0);
                c1 = fmaf(h[cur][k4 * 4 + 1], Wk[1 * DD], c1);
                c2 = fmaf(h[cur][k4 * 4 + 2], Wk[2 * DD], c2);
                c3 = fmaf(h[cur][k4 * 4 + 3], Wk[3 * DD], c3);
            }
            float a = ((c0 + c1) + (c2 + c3)) + bsv[l * DD + t];
            if (l < 2) {
                h[cur ^ 1][t] = fmaxf(a, 0.f);   // double buffer: no WAR
                cur ^= 1;
                __syncthreads();
            } else {
                hsh[t] = a;                      // winner keeps h locally
                ST_A(&hws[b * DD + t], a);       // sc1 write-through
            }
        }
        __syncthreads();                // vmcnt(0): hws at coherence point
        if (t == 0)
            ST_A(&flag[b], 1u);
    } else {
        // ---- wait for this b's h ----
        if (t == 0) {
            int guard = 40000;          // ~17ms bound; never hit if correct
            while (LD_A(&flag[b]) != 1u) {      // relaxed poll: NO buffer_inv
                if (--guard == 0) break;
                __builtin_amdgcn_s_sleep(16);   // ~0.43us backoff
            }
        }
        __syncthreads();
        hsh[t] = LD_A(&hws[b * DD + t]);        // sc1 load, post-flag
    }
    __syncthreads();
    const f4 hv = ((const f4*)hsh)[c];

    // ---- Phase C: out0 = regs + h[b]; zero nf re-read, nontemporal ----
#pragma unroll
    for (int i = 0; i < 5; i++) {
        const int n = s * RPS + i * 4 + r4;
        const int idx = (b * NN + n) * (DD / 4) + c;
        f4 o = vv[i] + hv;
        __builtin_nontemporal_store(o, &out0_4[idx]);
    }
}

extern "C" void kernel_launch(void* const* d_in, const int* in_sizes, int n_in,
                              void* d_out, int out_size, void* d_ws, size_t ws_size,
                              hipStream_t stream) {
    const f4* nf4   = (const f4*)d_in[1];        // node_feature
    const float* Ws = (const float*)d_in[2];     // (L,D,D)
    const float* bsv= (const float*)d_in[3];     // (L,D)
    f4* out0 = (f4*)d_out;
    f4* out1 = (f4*)((float*)d_out + ELEMS);

    float* partials = (float*)d_ws;                // SS*BB*DD floats (1.6 MB)
    float* hws      = partials + SS * BB * DD;     // BB*DD floats (32 KB)
    unsigned* sync  = (unsigned*)(hws + BB * DD);  // 64 words: ctr[32] | flag[32]
    unsigned* ctr   = sync;
    unsigned* flag  = sync + BB;

    k_init<<<1, 64, 0, stream>>>(sync);
    k_all<<<dim3(SS, BB), 256, 0, stream>>>(nf4, Ws, bsv, out0, out1,
                                            partials, hws, ctr, flag);
}

// Round 8
// 134.317 us; speedup vs baseline: 1.2327x; 1.2327x over previous
//
#include <hip/hip_runtime.h>

// (B,N,D,L) = (32,1000,256,3), all fp32.
// d_in: [0]=x (unused), [1]=node_feature, [2]=Ws (L,D,D), [3]=bs (L,D).
// Math collapses (A_norm = ones/N):
//   h[b,:] = MLP(mean_n nf[b,n,:]);  out0 = nf + h (broadcast);  out1 = nf.
//
// R7 post-mortem: fused spin-sync kernel stuck at 77-79us with ~50us of
// unexplained wait, resistant to two targeted fixes (W-warm, ILP, NT). Model
// failed twice => abandon the opaque structure. R8: back to stream-ordered
// 3-dispatch pipeline (observable per-dispatch timing, zero atomics/spins;
// cross-dispatch visibility is the runtime's end-of-kernel release):
//   k1: out1 = nf copy + partial column sums + distributed W-warm (every
//       XCD's ~100 blocks together pull all 768KB of W into that XCD's L2)
//   k2: 32-block MLP, 4-chain ILP GEMV per layer (W now L2-hot everywhere)
//   k3: out0 = nf + h[b] (nf L3-warm from k1)
#define BB 32
#define NN 1000
#define DD 256
#define SS 25                   // chunks per batch; SS*RPS == NN
#define RPS 40                  // rows per chunk
#define ELEMS (BB * NN * DD)    // 8,192,000 floats per output tensor
#define WF4 (3 * DD * DD / 4)   // 49152 float4 in Ws

typedef float f4 __attribute__((ext_vector_type(4)));

// ---- K1: partial column sums + out1 = nf + W-warm, one coalesced pass ----
// grid (SS, BB) = 800 blocks, 256 thr. Thread t: row-group r4 = t>>6, col c = t&63.
__global__ __launch_bounds__(256) void k_sumcopy(const f4* __restrict__ nf4,
                                                 f4* __restrict__ out1_4,
                                                 float* __restrict__ partials,
                                                 const f4* __restrict__ W4) {
    const int s = blockIdx.x, b = blockIdx.y, t = threadIdx.x;
    const int r4 = t >> 6, c = t & 63;
    f4 acc = (f4)(0.f);
#pragma unroll
    for (int i = 0; i < RPS / 4; i++) {            // 10 iters of 4 rows
        const int n = s * RPS + i * 4 + r4;
        const int idx = (b * NN + n) * (DD / 4) + c;
        f4 v = nf4[idx];
        out1_4[idx] = v;                           // output 1 (= nf), same pass
        acc += v;
    }
    // W-warm: 2 f4/thread, 512 f4/block; ~100 blocks/XCD x 512 >= 49152 f4
    // => every XCD L2 holds all of W before k2 runs. Plain cached loads.
    {
        const int bid = b * SS + s;
#pragma unroll
        for (int i = 0; i < 2; i++) {
            const int idx = (bid * 512 + i * 256 + t) % WF4;
            f4 w = W4[idx];
            asm volatile("" :: "v"(w.x), "v"(w.y), "v"(w.z), "v"(w.w));
        }
    }
    __shared__ float red[1024];
    ((f4*)red)[r4 * 64 + c] = acc;                 // red[r4*256 + c*4 + j]
    __syncthreads();
    // thread t owns dim d == t; plain store (visible to k2 via dispatch order)
    partials[(b * SS + s) * DD + t] =
        red[t] + red[256 + t] + red[512 + t] + red[768 + t];
}

// ---- K2: whole 3-layer MLP, one block per batch row, latency-optimized ----
__global__ __launch_bounds__(256) void k_mlp(const float* __restrict__ partials,
                                             const float* __restrict__ Ws,
                                             const float* __restrict__ bsv,
                                             float* __restrict__ hrow) {
    const int b = blockIdx.x, t = threadIdx.x;
    __shared__ float h[2][DD];

    // reduce SS=25 partials, 4 chains for load pipelining
    float a0 = 0.f, a1 = 0.f, a2 = 0.f, a3 = 0.f;
#pragma unroll
    for (int sp = 0; sp < 24; sp += 4) {
        a0 += partials[(b * SS + sp + 0) * DD + t];
        a1 += partials[(b * SS + sp + 1) * DD + t];
        a2 += partials[(b * SS + sp + 2) * DD + t];
        a3 += partials[(b * SS + sp + 3) * DD + t];
    }
    a0 += partials[(b * SS + 24) * DD + t];
    h[0][t] = ((a0 + a1) + (a2 + a3)) * (1.0f / (float)NN);
    __syncthreads();

    int cur = 0;
    for (int l = 0; l < 3; l++) {
        const float* __restrict__ W = Ws + l * DD * DD;
        float c0 = 0.f, c1 = 0.f, c2 = 0.f, c3 = 0.f;   // FMA chain 256 -> 64
#pragma unroll 8
        for (int k4 = 0; k4 < DD / 4; k4++) {
            const float* Wk = W + (k4 * 4) * DD + t;    // L2-hot (k1 warm)
            c0 = fmaf(h[cur][k4 * 4 + 0], Wk[0 * DD], c0);
            c1 = fmaf(h[cur][k4 * 4 + 1], Wk[1 * DD], c1);
            c2 = fmaf(h[cur][k4 * 4 + 2], Wk[2 * DD], c2);
            c3 = fmaf(h[cur][k4 * 4 + 3], Wk[3 * DD], c3);
        }
        float a = ((c0 + c1) + (c2 + c3)) + bsv[l * DD + t];
        if (l < 2) {
            h[cur ^ 1][t] = fmaxf(a, 0.f);              // double buffer
            cur ^= 1;
            __syncthreads();
        } else {
            hrow[b * DD + t] = a;                       // plain store
        }
    }
}

// ---- K3: out0 = nf + broadcast(h[b]). nf is L3-warm after k1. ----
__global__ __launch_bounds__(256) void k_out0(const f4* __restrict__ nf4,
                                              const float* __restrict__ hrow,
                                              f4* __restrict__ out0_4) {
    const int i = blockIdx.x * 256 + threadIdx.x;  // f4-chunk id, 2,048,000
    const int e = i * 4;
    const int b = e / (NN * DD);
    const int d0 = e & (DD - 1);                   // multiple of 4
    f4 v = nf4[i];
    const f4 hv = *(const f4*)(hrow + b * DD + d0);
    out0_4[i] = v + hv;
}

extern "C" void kernel_launch(void* const* d_in, const int* in_sizes, int n_in,
                              void* d_out, int out_size, void* d_ws, size_t ws_size,
                              hipStream_t stream) {
    const f4* nf4    = (const f4*)d_in[1];       // node_feature
    const float* Ws  = (const float*)d_in[2];    // (L,D,D)
    const float* bsv = (const float*)d_in[3];    // (L,D)
    f4* out0 = (f4*)d_out;
    f4* out1 = (f4*)((float*)d_out + ELEMS);

    float* partials = (float*)d_ws;              // SS*BB*DD floats (0.8 MB)
    float* hrow     = partials + SS * BB * DD;   // BB*DD floats (32 KB)

    k_sumcopy<<<dim3(SS, BB), 256, 0, stream>>>(nf4, out1, partials, (const f4*)Ws);
    k_mlp<<<BB, 256, 0, stream>>>(partials, Ws, bsv, hrow);
    k_out0<<<(ELEMS / 4) / 256, 256, 0, stream>>>(nf4, hrow, out0);
}

// Round 9
// 131.008 us; speedup vs baseline: 1.2639x; 1.0253x over previous
//
#include <hip/hip_runtime.h>

// (B,N,D,L) = (32,1000,256,3), all fp32.
// d_in: [0]=x (unused), [1]=node_feature, [2]=Ws (L,D,D), [3]=bs (L,D).
// Math collapses (A_norm = ones/N):
//   h[b,:] = MLP(mean_n nf[b,n,:]);  out0 = nf + h (broadcast);  out1 = nf.
//
// R8 post-mortem: 3-dispatch pipeline = 134us; fills ~51us + work ~29us +
// ~54us of dispatch-boundary overhead (~10-15us/boundary). R9 cuts another
// boundary (3 -> 2 dispatches): every out0 block REDUNDANTLY computes the
// 3-layer MLP for its own batch (W is L2-hot from k1's distributed warm;
// 320 x 768KB = 246MB of L2 reads ~ 7us aggregate, zero extra HBM), then
// streams its out0 slice. No cross-block sync anywhere; k1->k2 visibility is
// stream dispatch order. NT stores for both outputs keep W/nf cached.
#define BB 32
#define NN 1000
#define DD 256
#define SS 25                   // k1 chunks per batch; SS*RPS == NN
#define RPS 40                  // rows per k1 chunk
#define OS 10                   // k2 slices per batch
#define OF4 (NN * DD / 4 / OS)  // 6400 f4 per k2 block; 25 per thread
#define ELEMS (BB * NN * DD)    // 8,192,000 floats per output tensor
#define WF4 (3 * DD * DD / 4)   // 49152 float4 in Ws

typedef float f4 __attribute__((ext_vector_type(4)));

// ---- K1: partial column sums + out1 = nf + W-warm, one coalesced pass ----
// grid (SS, BB) = 800 blocks, 256 thr. Thread t: row-group r4 = t>>6, col c = t&63.
__global__ __launch_bounds__(256) void k_sumcopy(const f4* __restrict__ nf4,
                                                 f4* __restrict__ out1_4,
                                                 float* __restrict__ partials,
                                                 const f4* __restrict__ W4) {
    const int s = blockIdx.x, b = blockIdx.y, t = threadIdx.x;
    const int r4 = t >> 6, c = t & 63;
    f4 acc = (f4)(0.f);
#pragma unroll
    for (int i = 0; i < RPS / 4; i++) {            // 10 iters of 4 rows
        const int n = s * RPS + i * 4 + r4;
        const int idx = (b * NN + n) * (DD / 4) + c;
        f4 v = nf4[idx];                           // plain: leaves nf in L3 for k2
        __builtin_nontemporal_store(v, &out1_4[idx]);  // out1 never re-read
        acc += v;
    }
    // W-warm: 2 f4/thread, 512 f4/block; ~100 blocks/XCD x 512 >= 49152 f4
    // => every XCD L2 holds all of W before k2 runs. Plain cached loads.
    {
        const int bid = b * SS + s;
#pragma unroll
        for (int i = 0; i < 2; i++) {
            const int idx = (bid * 512 + i * 256 + t) % WF4;
            f4 w = W4[idx];
            asm volatile("" :: "v"(w.x), "v"(w.y), "v"(w.z), "v"(w.w));
        }
    }
    __shared__ float red[1024];
    ((f4*)red)[r4 * 64 + c] = acc;                 // red[r4*256 + c*4 + j]
    __syncthreads();
    // thread t owns dim d == t; plain store (visible to k2 via dispatch order)
    partials[(b * SS + s) * DD + t] =
        red[t] + red[256 + t] + red[512 + t] + red[768 + t];
}

// ---- K2: redundant per-block MLP (L2-hot W), then stream out0 slice ----
// grid (OS, BB) = 320 blocks, 256 thr.
__global__ __launch_bounds__(256) void k_mlp_out0(const f4* __restrict__ nf4,
                                                  const float* __restrict__ partials,
                                                  const float* __restrict__ Ws,
                                                  const float* __restrict__ bsv,
                                                  f4* __restrict__ out0_4) {
    const int s = blockIdx.x, b = blockIdx.y, t = threadIdx.x;
    __shared__ float h[2][DD];
    __shared__ float hfin[DD];

    // reduce SS=25 partials, 4 chains for load pipelining
    float a0 = 0.f, a1 = 0.f, a2 = 0.f, a3 = 0.f;
#pragma unroll
    for (int sp = 0; sp < 24; sp += 4) {
        a0 += partials[(b * SS + sp + 0) * DD + t];
        a1 += partials[(b * SS + sp + 1) * DD + t];
        a2 += partials[(b * SS + sp + 2) * DD + t];
        a3 += partials[(b * SS + sp + 3) * DD + t];
    }
    a0 += partials[(b * SS + 24) * DD + t];
    h[0][t] = ((a0 + a1) + (a2 + a3)) * (1.0f / (float)NN);
    __syncthreads();

    int cur = 0;
    for (int l = 0; l < 3; l++) {
        const float* __restrict__ W = Ws + l * DD * DD;
        float c0 = 0.f, c1 = 0.f, c2 = 0.f, c3 = 0.f;   // FMA chain 256 -> 64
#pragma unroll 8
        for (int k4 = 0; k4 < DD / 4; k4++) {
            const float* Wk = W + (k4 * 4) * DD + t;    // L2-hot (k1 warm)
            c0 = fmaf(h[cur][k4 * 4 + 0], Wk[0 * DD], c0);
            c1 = fmaf(h[cur][k4 * 4 + 1], Wk[1 * DD], c1);
            c2 = fmaf(h[cur][k4 * 4 + 2], Wk[2 * DD], c2);
            c3 = fmaf(h[cur][k4 * 4 + 3], Wk[3 * DD], c3);
        }
        float a = ((c0 + c1) + (c2 + c3)) + bsv[l * DD + t];
        if (l < 2) {
            h[cur ^ 1][t] = fmaxf(a, 0.f);              // double buffer
            cur ^= 1;
            __syncthreads();
        } else {
            hfin[t] = a;                                // deterministic: same
            __syncthreads();                            // result in every block
        }
    }

    // stream this block's out0 slice: f4 j = s*OF4 + i*256 + t within batch b.
    // (s*OF4) % 64 == 0 and 256 % 64 == 0 => dim-f4 index is t & 63, constant.
    const f4 hv = ((const f4*)hfin)[t & 63];
    const int base = b * (NN * DD / 4) + s * OF4 + t;
#pragma unroll
    for (int i = 0; i < OF4 / 256; i++) {               // 25 iters
        f4 v = nf4[base + i * 256];                     // L3-warm from k1
        __builtin_nontemporal_store(v + hv, &out0_4[base + i * 256]);
    }
}

extern "C" void kernel_launch(void* const* d_in, const int* in_sizes, int n_in,
                              void* d_out, int out_size, void* d_ws, size_t ws_size,
                              hipStream_t stream) {
    const f4* nf4    = (const f4*)d_in[1];       // node_feature
    const float* Ws  = (const float*)d_in[2];    // (L,D,D)
    const float* bsv = (const float*)d_in[3];    // (L,D)
    f4* out0 = (f4*)d_out;
    f4* out1 = (f4*)((float*)d_out + ELEMS);

    float* partials = (float*)d_ws;              // SS*BB*DD floats (0.8 MB)

    k_sumcopy<<<dim3(SS, BB), 256, 0, stream>>>(nf4, out1, partials, (const f4*)Ws);
    k_mlp_out0<<<dim3(OS, BB), 256, 0, stream>>>(nf4, partials, Ws, bsv, out0);
}